// Round 23
// baseline (142.133 us; speedup 1.0000x reference)
//
#include <hip/hip_runtime.h>
#include <math.h>

#define S_LEN 2048
#define DMODEL 1024
#define NHEADS 16
#define DK 64

// q-projection scale: 1/sqrt(dk) * log2(e)  -> softmax works in exp2 domain
#define QSCALE 0.1803368801111244f

typedef __attribute__((ext_vector_type(8))) _Float16 f16x8;
typedef __attribute__((ext_vector_type(2))) __fp16 hf16x2;
typedef __attribute__((ext_vector_type(4))) float f32x4;

static __device__ __forceinline__ unsigned short f2h(float f) {
    _Float16 h = (_Float16)f;
    return __builtin_bit_cast(unsigned short, h);
}

static __device__ __forceinline__ unsigned pack2(float a, float b) {
    hf16x2 h = __builtin_amdgcn_cvt_pkrtz(a, b);
    return __builtin_bit_cast(unsigned, h);
}

static __device__ __forceinline__ void gload16(const void* g, void* l) {
    __builtin_amdgcn_global_load_lds(
        (const __attribute__((address_space(1))) void*)g,
        (__attribute__((address_space(3))) void*)l, 16, 0, 0);
}

// ---------------------------------------------------------------------------
// W [1024][1024] fp32 -> Wt [n][k] fp16 (transposed), LDS-tiled 64x64.
// ---------------------------------------------------------------------------
__global__ __launch_bounds__(256)
void wprep_kernel(const float* __restrict__ w0, const float* __restrict__ w1,
                  const float* __restrict__ w2, const float* __restrict__ w3,
                  unsigned short* __restrict__ wt)
{
    __shared__ float tile[64][65];
    const int z = blockIdx.z;
    const float* W = z == 0 ? w0 : (z == 1 ? w1 : (z == 2 ? w2 : w3));
    unsigned short* Wt = wt + (size_t)z * 1048576;
    const int k0 = blockIdx.x * 64, n0 = blockIdx.y * 64;
    const int t = threadIdx.x;
    #pragma unroll
    for (int i = 0; i < 4; ++i) {
        int idx = i * 256 + t;
        int r = idx >> 4, c4 = (idx & 15) * 4;
        float4 v = *reinterpret_cast<const float4*>(W + (size_t)(k0 + r) * 1024 + n0 + c4);
        tile[r][c4 + 0] = v.x; tile[r][c4 + 1] = v.y;
        tile[r][c4 + 2] = v.z; tile[r][c4 + 3] = v.w;
    }
    __syncthreads();
    #pragma unroll
    for (int i = 0; i < 4; ++i) {
        int idx = i * 256 + t;
        int nr = idx >> 4, kc4 = (idx & 15) * 4;
        ushort4 h;
        h.x = f2h(tile[kc4 + 0][nr]); h.y = f2h(tile[kc4 + 1][nr]);
        h.z = f2h(tile[kc4 + 2][nr]); h.w = f2h(tile[kc4 + 3][nr]);
        *reinterpret_cast<ushort4*>(Wt + (size_t)(n0 + nr) * 1024 + k0 + kc4) = h;
    }
}

// ---------------------------------------------------------------------------
// Fused projection GEMM (cvt in A-staging), tile 128x64, 512 thr / 8 waves
// (4m x 2n), grid (8, 64, 3) = 1536 blocks -> 4 blocks/CU (32 waves, 100%
// static occupancy; proj is latency-bound with VGPR/LDS headroom — R22
// counters). XCD decode: mtile = x + 8*(y>>4), ntile = y&15; all 16 N-blocks
// of an A-tile share (id mod 8) -> same XCD, A L2-reuse preserved (R15).
// ---------------------------------------------------------------------------
__global__ __launch_bounds__(512)
void proj_gemm_kernel(const float* __restrict__ x0, const float* __restrict__ x1,
                      const float* __restrict__ x2,
                      const unsigned short* __restrict__ wt_base,
                      const float* __restrict__ b0, const float* __restrict__ b1,
                      const float* __restrict__ b2,
                      unsigned short* __restrict__ dst_base)
{
    __shared__ char Als[16384];   // 128 rows x 64 k fp16, swizzled
    __shared__ char Bls[8192];    // 64 n   x 64 k fp16, swizzled

    const int z = blockIdx.z;
    const float* Ag = z == 0 ? x0 : (z == 1 ? x1 : x2);
    const char* Bg = (const char*)(wt_base + (size_t)z * 1048576);
    const float* bias = z == 0 ? b0 : (z == 1 ? b1 : b2);
    const int mode = z;

    const int tid = threadIdx.x;
    const int w = tid >> 6, l = tid & 63, a = l & 15, g = l >> 4;
    const int wm = w >> 1, wn = w & 1;            // 4 x 2 wave grid
    const int ntile = blockIdx.y & 15;
    const int mtile = blockIdx.x + ((blockIdx.y >> 4) << 3);
    const int bm = mtile * 128, bn = ntile * 64;

    const int arow = tid >> 2;
    const int ac16 = tid & 3;
    const int aswz = (arow & 7) << 4;
    const int srow = tid >> 3;                    // 0..63 (B rows)
    const int sc8 = tid & 7;

    f32x4 acc[2][2] = {};

    for (int ks = 0; ks < 16; ++ks) {
        const float* ap = Ag + (size_t)(bm + arow) * 1024 + ks * 64 + 16 * ac16;
        float4 a0 = reinterpret_cast<const float4*>(ap)[0];
        float4 a1 = reinterpret_cast<const float4*>(ap)[1];
        float4 a2 = reinterpret_cast<const float4*>(ap)[2];
        float4 a3 = reinterpret_cast<const float4*>(ap)[3];

        // B: one async 16B per thread covers the 64x128B tile
        {
            const int gc = (sc8 << 4) ^ ((srow & 7) << 4);
            gload16(Bg + (size_t)(bn + srow) * 2048 + ks * 128 + gc,
                    &Bls[(size_t)tid * 16]);
        }

        uint4 w0, w1;
        w0.x = pack2(a0.x, a0.y); w0.y = pack2(a0.z, a0.w);
        w0.z = pack2(a1.x, a1.y); w0.w = pack2(a1.z, a1.w);
        w1.x = pack2(a2.x, a2.y); w1.y = pack2(a2.z, a2.w);
        w1.z = pack2(a3.x, a3.y); w1.w = pack2(a3.z, a3.w);
        const int abase = arow * 128;
        const int aoff = 32 * ac16;
        *reinterpret_cast<uint4*>(&Als[abase + (aoff ^ aswz)]) = w0;
        *reinterpret_cast<uint4*>(&Als[abase + ((aoff + 16) ^ aswz)]) = w1;

        __syncthreads();
        #pragma unroll
        for (int kc = 0; kc < 2; ++kc) {
            f16x8 af[2], bf[2];
            #pragma unroll
            for (int mi = 0; mi < 2; ++mi) {
                const int row = wm * 32 + 16 * mi + a;
                af[mi] = *reinterpret_cast<const f16x8*>(
                    &Als[row * 128 + ((kc * 64 + g * 16) ^ ((row & 7) << 4))]);
            }
            #pragma unroll
            for (int ni = 0; ni < 2; ++ni) {
                const int row = wn * 32 + 16 * ni + a;
                bf[ni] = *reinterpret_cast<const f16x8*>(
                    &Bls[row * 128 + ((kc * 64 + g * 16) ^ ((row & 7) << 4))]);
            }
            __builtin_amdgcn_s_setprio(1);
            #pragma unroll
            for (int mi = 0; mi < 2; ++mi)
                #pragma unroll
                for (int ni = 0; ni < 2; ++ni)
                    acc[mi][ni] = __builtin_amdgcn_mfma_f32_16x16x32_f16(
                        af[mi], bf[ni], acc[mi][ni], 0, 0, 0);
            __builtin_amdgcn_s_setprio(0);
        }
        __syncthreads();
    }

    unsigned short* mydst = dst_base + (size_t)z * 4194304;

    #pragma unroll
    for (int ni = 0; ni < 2; ++ni) {
        const int n = bn + wn * 32 + 16 * ni + a;
        const float bv = bias[n];
        #pragma unroll
        for (int mi = 0; mi < 2; ++mi) {
            const int mbase = bm + wm * 32 + 16 * mi + g * 4;
            if (mode == 2) {
                const int b = mbase >> 11, s = mbase & (S_LEN - 1);
                const int h = n >> 6, d = n & (DK - 1);
                ushort4 st;
                st.x = f2h(acc[mi][ni][0] + bv);
                st.y = f2h(acc[mi][ni][1] + bv);
                st.z = f2h(acc[mi][ni][2] + bv);
                st.w = f2h(acc[mi][ni][3] + bv);
                *reinterpret_cast<ushort4*>(
                    mydst + ((size_t)((b * NHEADS + h) * DK + d)) * S_LEN + s) = st;
            } else {
                const float sc = (mode == 0) ? QSCALE : 1.0f;
                #pragma unroll
                for (int r = 0; r < 4; ++r) {
                    const int m = mbase + r;
                    const int b = m >> 11, s = m & (S_LEN - 1);
                    const int h = n >> 6, d = n & (DK - 1);
                    mydst[((size_t)((b * NHEADS + h) * S_LEN + s)) * DK + d] =
                        f2h((acc[mi][ni][r] + bv) * sc);
                }
            }
        }
    }
}

// ---------------------------------------------------------------------------
// Output GEMM (proven R15 — frozen).
// ---------------------------------------------------------------------------
__global__ __launch_bounds__(512)
void out_gemm_kernel(const unsigned short* __restrict__ Agh,
                     const unsigned short* __restrict__ Bgh,
                     const float* __restrict__ bias, float* __restrict__ out)
{
    __shared__ char Als[16384];
    __shared__ char Bls[16384];

    const char* Ag = (const char*)Agh;
    const char* Bg = (const char*)Bgh;

    const int tid = threadIdx.x;
    const int w = tid >> 6, l = tid & 63, a = l & 15, g = l >> 4;
    const int wm = w >> 2, wn = w & 3;
    const int ntile = blockIdx.y & 7;
    const int mtile = blockIdx.x + ((blockIdx.y >> 3) << 3);
    const int bm = mtile * 128, bn = ntile * 128;

    const int srow = tid >> 3;
    const int sc8 = tid & 7;

    f32x4 acc[4][2] = {};

    for (int k0b = 0; k0b < 2048; k0b += 128) {
        #pragma unroll
        for (int it = 0; it < 2; ++it) {
            const int row = it * 64 + srow;
            const int gc = (sc8 << 4) ^ ((row & 7) << 4);
            gload16(Ag + (size_t)(bm + row) * 2048 + k0b + gc,
                    &Als[(size_t)(it * 512 + tid) * 16]);
            gload16(Bg + (size_t)(bn + row) * 2048 + k0b + gc,
                    &Bls[(size_t)(it * 512 + tid) * 16]);
        }
        __syncthreads();
        #pragma unroll
        for (int kc = 0; kc < 2; ++kc) {
            f16x8 af[4], bf[2];
            #pragma unroll
            for (int mi = 0; mi < 4; ++mi) {
                const int row = wm * 64 + 16 * mi + a;
                af[mi] = *reinterpret_cast<const f16x8*>(
                    &Als[row * 128 + ((kc * 64 + g * 16) ^ ((row & 7) << 4))]);
            }
            #pragma unroll
            for (int ni = 0; ni < 2; ++ni) {
                const int row = wn * 32 + 16 * ni + a;
                bf[ni] = *reinterpret_cast<const f16x8*>(
                    &Bls[row * 128 + ((kc * 64 + g * 16) ^ ((row & 7) << 4))]);
            }
            __builtin_amdgcn_s_setprio(1);
            #pragma unroll
            for (int mi = 0; mi < 4; ++mi)
                #pragma unroll
                for (int ni = 0; ni < 2; ++ni)
                    acc[mi][ni] = __builtin_amdgcn_mfma_f32_16x16x32_f16(
                        af[mi], bf[ni], acc[mi][ni], 0, 0, 0);
            __builtin_amdgcn_s_setprio(0);
        }
        __syncthreads();
    }

    #pragma unroll
    for (int ni = 0; ni < 2; ++ni) {
        const int n = bn + wn * 32 + 16 * ni + a;
        const float bv = bias[n];
        #pragma unroll
        for (int mi = 0; mi < 4; ++mi) {
            const int mbase = bm + wm * 64 + 16 * mi + g * 4;
            #pragma unroll
            for (int r = 0; r < 4; ++r)
                out[(size_t)(mbase + r) * 1024 + n] = acc[mi][ni][r] + bv;
        }
    }
}

// ---------------------------------------------------------------------------
// MFMA flash attention v4 (exact R12/R15/R20 structure — proven best, frozen).
// ---------------------------------------------------------------------------
__global__ __launch_bounds__(512, 4)
void attn_mfma_kernel(const unsigned short* __restrict__ qb,
                      const unsigned short* __restrict__ kb,
                      const unsigned short* __restrict__ vt,
                      unsigned short* __restrict__ ob)
{
    __shared__ char Kls[2][8192];
    __shared__ char Vls[2][8192];
    __shared__ unsigned short Pl[8][32][72];

    const int tid = threadIdx.x;
    const int w = tid >> 6;          // 0..7
    const int p = w >> 2;            // kv parity of this wave
    const int wsub = w & 3;
    const int l = tid & 63;
    const int a = l & 15;
    const int g = l >> 4;
    const int bh = blockIdx.y;
    const int q0 = blockIdx.x * 128 + wsub * 32;

    const unsigned short* qhead = qb + (size_t)bh * S_LEN * DK;
    const char* khead = (const char*)(kb + (size_t)bh * S_LEN * DK);
    const char* vhead = (const char*)(vt + (size_t)bh * DK * S_LEN);

    f16x8 qf[2][2];
    #pragma unroll
    for (int j = 0; j < 2; ++j)
        #pragma unroll
        for (int c = 0; c < 2; ++c)
            qf[j][c] = *reinterpret_cast<const f16x8*>(
                qhead + (size_t)(q0 + 16 * j + a) * DK + 32 * c + 8 * g);

    f16x8 onesf;
    #pragma unroll
    for (int i = 0; i < 8; ++i) onesf[i] = (_Float16)1.f;

    f32x4 oacc[4][2] = {};
    f32x4 lacc[2] = {};
    float mrun[2] = {-INFINITY, -INFINITY};

    const int srow = tid >> 3;                                  // 0..63
    const int sgc = ((tid & 7) << 4) ^ ((srow & 7) << 4);       // swizzled col

    #define STAGE1(t2)                                                          \
        do {                                                                    \
            gload16(khead + (size_t)((t2) * 64 + srow) * 128 + sgc,             \
                    &Kls[(t2) & 1][(size_t)w * 1024]);                          \
            gload16(vhead + (size_t)srow * 4096 + (size_t)(t2) * 128 + sgc,     \
                    &Vls[(t2) & 1][(size_t)w * 1024]);                          \
        } while (0)

    STAGE1(0);
    STAGE1(1);
    __syncthreads();

    for (int i = 0; i < 16; ++i) {
        f16x8 kf[2][4];
        #pragma unroll
        for (int c = 0; c < 2; ++c)
            #pragma unroll
            for (int T = 0; T < 4; ++T) {
                const int row = 16 * T + a;
                kf[c][T] = *reinterpret_cast<const f16x8*>(
                    &Kls[p][row * 128 + ((64 * c + 16 * g) ^ ((row & 7) << 4))]);
            }

        #pragma unroll
        for (int j = 0; j < 2; ++j) {
            f32x4 sacc[4] = {};
            __builtin_amdgcn_s_setprio(1);
            #pragma unroll
            for (int c = 0; c < 2; ++c)
                #pragma unroll
                for (int T = 0; T < 4; ++T)
                    sacc[T] = __builtin_amdgcn_mfma_f32_16x16x32_f16(
                        kf[c][T], qf[j][c], sacc[T], 0, 0, 0);
            __builtin_amdgcn_s_setprio(0);

            float lm = -INFINITY;
            #pragma unroll
            for (int T = 0; T < 4; ++T)
                #pragma unroll
                for (int r = 0; r < 4; ++r) lm = fmaxf(lm, sacc[T][r]);

            if (!__all(lm <= mrun[j] + 8.f)) {
                float vmax = fmaxf(lm, __shfl_xor(lm, 16));
                vmax = fmaxf(vmax, __shfl_xor(vmax, 32));
                const float mnew = fmaxf(mrun[j], vmax);
                const float corr = __builtin_amdgcn_exp2f(mrun[j] - mnew);
                #pragma unroll
                for (int t = 0; t < 4; ++t) {
                    oacc[t][j][0] *= corr; oacc[t][j][1] *= corr;
                    oacc[t][j][2] *= corr; oacc[t][j][3] *= corr;
                }
                lacc[j][0] *= corr; lacc[j][1] *= corr;
                lacc[j][2] *= corr; lacc[j][3] *= corr;
                mrun[j] = mnew;
            }

            const float mj = mrun[j];
            #pragma unroll
            for (int T = 0; T < 4; ++T) {
                float e0 = __builtin_amdgcn_exp2f(sacc[T][0] - mj);
                float e1 = __builtin_amdgcn_exp2f(sacc[T][1] - mj);
                float e2 = __builtin_amdgcn_exp2f(sacc[T][2] - mj);
                float e3 = __builtin_amdgcn_exp2f(sacc[T][3] - mj);
                unsigned* dst = reinterpret_cast<unsigned*>(
                    &Pl[w][16 * j + a][16 * T + 4 * g]);
                dst[0] = pack2(e0, e1);
                dst[1] = pack2(e2, e3);
            }
        }

        f16x8 vf[2][4];
        #pragma unroll
        for (int c = 0; c < 2; ++c)
            #pragma unroll
            for (int t = 0; t < 4; ++t) {
                const int row = 16 * t + a;
                vf[c][t] = *reinterpret_cast<const f16x8*>(
                    &Vls[p][row * 128 + ((64 * c + 16 * g) ^ ((row & 7) << 4))]);
            }

        __syncthreads();
        if (i < 15) {
            STAGE1(2 * i + 2);
            STAGE1(2 * i + 3);
        }

        #pragma unroll
        for (int c = 0; c < 2; ++c) {
            f16x8 pf[2];
            #pragma unroll
            for (int j = 0; j < 2; ++j)
                pf[j] = *reinterpret_cast<const f16x8*>(
                    &Pl[w][16 * j + a][32 * c + 8 * g]);
            __builtin_amdgcn_s_setprio(1);
            #pragma unroll
            for (int t = 0; t < 4; ++t)
                #pragma unroll
                for (int j = 0; j < 2; ++j)
                    oacc[t][j] = __builtin_amdgcn_mfma_f32_16x16x32_f16(
                        vf[c][t], pf[j], oacc[t][j], 0, 0, 0);
            #pragma unroll
            for (int j = 0; j < 2; ++j)
                lacc[j] = __builtin_amdgcn_mfma_f32_16x16x32_f16(
                    onesf, pf[j], lacc[j], 0, 0, 0);
            __builtin_amdgcn_s_setprio(0);
        }
        __syncthreads();
    }
    #undef STAGE1

    float* Ob = (float*)Pl;
    float* Ml = (float*)Kls;
    if (p == 1) {
        #pragma unroll
        for (int j = 0; j < 2; ++j) {
            if (g == 0) {
                Ml[((wsub * 2 + j) * 2 + 0) * 16 + a] = mrun[j];
                Ml[((wsub * 2 + j) * 2 + 1) * 16 + a] = lacc[j][0];
            }
            #pragma unroll
            for (int t = 0; t < 4; ++t)
                #pragma unroll
                for (int r = 0; r < 4; ++r)
                    Ob[((wsub * 2 + j) * 64 + 16 * t + 4 * g + r) * 16 + a] =
                        oacc[t][j][r];
        }
    }
    __syncthreads();
    if (p == 0) {
        const int b = bh >> 4;
        const int h = bh & (NHEADS - 1);
        #pragma unroll
        for (int j = 0; j < 2; ++j) {
            const float m1 = Ml[((wsub * 2 + j) * 2 + 0) * 16 + a];
            const float l1 = Ml[((wsub * 2 + j) * 2 + 1) * 16 + a];
            const float m0 = mrun[j];
            const float ms = fmaxf(m0, m1);
            const float c0 = __builtin_amdgcn_exp2f(m0 - ms);
            const float c1 = __builtin_amdgcn_exp2f(m1 - ms);
            const float inv = 1.f / (lacc[j][0] * c0 + l1 * c1);
            unsigned short* dst0 =
                ob + (size_t)(b * S_LEN + q0 + 16 * j + a) * DMODEL + h * DK;
            #pragma unroll
            for (int t = 0; t < 4; ++t) {
                ushort4 st;
                #pragma unroll
                for (int r = 0; r < 4; ++r) {
                    const float o1 =
                        Ob[((wsub * 2 + j) * 64 + 16 * t + 4 * g + r) * 16 + a];
                    const float val = (oacc[t][j][r] * c0 + o1 * c1) * inv;
                    ((unsigned short*)&st)[r] = f2h(val);
                }
                *reinterpret_cast<ushort4*>(dst0 + 16 * t + 4 * g) = st;
            }
        }
    }
}

// ---------------------------------------------------------------------------
extern "C" void kernel_launch(void* const* d_in, const int* in_sizes, int n_in,
                              void* d_out, int out_size, void* d_ws, size_t ws_size,
                              hipStream_t stream)
{
    const float* Q  = (const float*)d_in[0];
    const float* K  = (const float*)d_in[1];
    const float* V  = (const float*)d_in[2];
    const float* Wq = (const float*)d_in[3];
    const float* bq = (const float*)d_in[4];
    const float* Wk = (const float*)d_in[5];
    const float* bk = (const float*)d_in[6];
    const float* Wv = (const float*)d_in[7];
    const float* bv = (const float*)d_in[8];
    const float* Wo = (const float*)d_in[9];
    const float* bo = (const float*)d_in[10];
    float* out = (float*)d_out;

    // ws layout (fp16 elems): [unused 3*4M] wt[4*1M] qb[4M] kb[4M] vtb[4M] ob[4M]
    unsigned short* xh  = (unsigned short*)d_ws;
    unsigned short* wt  = xh + (size_t)3 * 4194304;
    unsigned short* qb  = wt + (size_t)4 * 1048576;
    unsigned short* kb  = qb + 4194304;
    unsigned short* vtb = kb + 4194304;
    unsigned short* obh = vtb + 4194304;

    wprep_kernel<<<dim3(16, 16, 4), 256, 0, stream>>>(Wq, Wk, Wv, Wo, wt);

    // proj: tile 128x64, grid (8, 64, 3) — 4 blocks/CU, XCD-mapped
    proj_gemm_kernel<<<dim3(8, 64, 3), 512, 0, stream>>>(
        Q, K, V, wt, bq, bk, bv, qb);

    attn_mfma_kernel<<<dim3(S_LEN / 128, 2 * NHEADS), 512, 0, stream>>>(qb, kb, vtb, obh);

    out_gemm_kernel<<<dim3(8, 32, 1), 512, 0, stream>>>(
        obh, wt + (size_t)3 * 1048576, bo, out);
}

// Round 24
// 120.794 us; speedup vs baseline: 1.1767x; 1.1767x over previous
//
#include <hip/hip_runtime.h>
#include <math.h>

#define S_LEN 2048
#define DMODEL 1024
#define NHEADS 16
#define DK 64

// q-projection scale: 1/sqrt(dk) * log2(e)  -> softmax works in exp2 domain
#define QSCALE 0.1803368801111244f

typedef __attribute__((ext_vector_type(8))) _Float16 f16x8;
typedef __attribute__((ext_vector_type(2))) __fp16 hf16x2;
typedef __attribute__((ext_vector_type(4))) float f32x4;

static __device__ __forceinline__ unsigned short f2h(float f) {
    _Float16 h = (_Float16)f;
    return __builtin_bit_cast(unsigned short, h);
}

static __device__ __forceinline__ unsigned pack2(float a, float b) {
    hf16x2 h = __builtin_amdgcn_cvt_pkrtz(a, b);
    return __builtin_bit_cast(unsigned, h);
}

static __device__ __forceinline__ void gload16(const void* g, void* l) {
    __builtin_amdgcn_global_load_lds(
        (const __attribute__((address_space(1))) void*)g,
        (__attribute__((address_space(3))) void*)l, 16, 0, 0);
}

// ---------------------------------------------------------------------------
// W [1024][1024] fp32 -> Wt [n][k] fp16 (transposed), LDS-tiled 64x64.
// ---------------------------------------------------------------------------
__global__ __launch_bounds__(256)
void wprep_kernel(const float* __restrict__ w0, const float* __restrict__ w1,
                  const float* __restrict__ w2, const float* __restrict__ w3,
                  unsigned short* __restrict__ wt)
{
    __shared__ float tile[64][65];
    const int z = blockIdx.z;
    const float* W = z == 0 ? w0 : (z == 1 ? w1 : (z == 2 ? w2 : w3));
    unsigned short* Wt = wt + (size_t)z * 1048576;
    const int k0 = blockIdx.x * 64, n0 = blockIdx.y * 64;
    const int t = threadIdx.x;
    #pragma unroll
    for (int i = 0; i < 4; ++i) {
        int idx = i * 256 + t;
        int r = idx >> 4, c4 = (idx & 15) * 4;
        float4 v = *reinterpret_cast<const float4*>(W + (size_t)(k0 + r) * 1024 + n0 + c4);
        tile[r][c4 + 0] = v.x; tile[r][c4 + 1] = v.y;
        tile[r][c4 + 2] = v.z; tile[r][c4 + 3] = v.w;
    }
    __syncthreads();
    #pragma unroll
    for (int i = 0; i < 4; ++i) {
        int idx = i * 256 + t;
        int nr = idx >> 4, kc4 = (idx & 15) * 4;
        ushort4 h;
        h.x = f2h(tile[kc4 + 0][nr]); h.y = f2h(tile[kc4 + 1][nr]);
        h.z = f2h(tile[kc4 + 2][nr]); h.w = f2h(tile[kc4 + 3][nr]);
        *reinterpret_cast<ushort4*>(Wt + (size_t)(n0 + nr) * 1024 + k0 + kc4) = h;
    }
}

// ---------------------------------------------------------------------------
// Fused projection GEMM (cvt in A-staging). Tile 128x128, 512 thr / 8 waves.
// XCD-aware decode (proven R15/R20/R22). No A-prefetch (R21 regressed),
// no smaller tile (R23 regressed): this shape is the measured optimum.
// ---------------------------------------------------------------------------
__global__ __launch_bounds__(512)
void proj_gemm_kernel(const float* __restrict__ x0, const float* __restrict__ x1,
                      const float* __restrict__ x2,
                      const unsigned short* __restrict__ wt_base,
                      const float* __restrict__ b0, const float* __restrict__ b1,
                      const float* __restrict__ b2,
                      unsigned short* __restrict__ dst_base)
{
    __shared__ char Als[16384];
    __shared__ char Bls[16384];

    const int z = blockIdx.z;
    const float* Ag = z == 0 ? x0 : (z == 1 ? x1 : x2);
    const char* Bg = (const char*)(wt_base + (size_t)z * 1048576);
    const float* bias = z == 0 ? b0 : (z == 1 ? b1 : b2);
    const int mode = z;

    const int tid = threadIdx.x;
    const int w = tid >> 6, l = tid & 63, a = l & 15, g = l >> 4;
    const int wm = w >> 2, wn = w & 3;
    const int ntile = blockIdx.y & 7;
    const int mtile = blockIdx.x + ((blockIdx.y >> 3) << 3);
    const int bm = mtile * 128, bn = ntile * 128;

    const int arow = tid >> 2;
    const int ac16 = tid & 3;
    const int aswz = (arow & 7) << 4;
    const int srow = tid >> 3;
    const int sc8 = tid & 7;

    f32x4 acc[4][2] = {};

    for (int ks = 0; ks < 16; ++ks) {
        const float* ap = Ag + (size_t)(bm + arow) * 1024 + ks * 64 + 16 * ac16;
        float4 a0 = reinterpret_cast<const float4*>(ap)[0];
        float4 a1 = reinterpret_cast<const float4*>(ap)[1];
        float4 a2 = reinterpret_cast<const float4*>(ap)[2];
        float4 a3 = reinterpret_cast<const float4*>(ap)[3];

        #pragma unroll
        for (int it = 0; it < 2; ++it) {
            const int row = it * 64 + srow;
            const int gc = (sc8 << 4) ^ ((row & 7) << 4);
            gload16(Bg + (size_t)(bn + row) * 2048 + ks * 128 + gc,
                    &Bls[(size_t)(it * 512 + tid) * 16]);
        }

        uint4 w0, w1;
        w0.x = pack2(a0.x, a0.y); w0.y = pack2(a0.z, a0.w);
        w0.z = pack2(a1.x, a1.y); w0.w = pack2(a1.z, a1.w);
        w1.x = pack2(a2.x, a2.y); w1.y = pack2(a2.z, a2.w);
        w1.z = pack2(a3.x, a3.y); w1.w = pack2(a3.z, a3.w);
        const int abase = arow * 128;
        const int aoff = 32 * ac16;
        *reinterpret_cast<uint4*>(&Als[abase + (aoff ^ aswz)]) = w0;
        *reinterpret_cast<uint4*>(&Als[abase + ((aoff + 16) ^ aswz)]) = w1;

        __syncthreads();
        #pragma unroll
        for (int kc = 0; kc < 2; ++kc) {
            f16x8 af[4], bf[2];
            #pragma unroll
            for (int mi = 0; mi < 4; ++mi) {
                const int row = wm * 64 + 16 * mi + a;
                af[mi] = *reinterpret_cast<const f16x8*>(
                    &Als[row * 128 + ((kc * 64 + g * 16) ^ ((row & 7) << 4))]);
            }
            #pragma unroll
            for (int ni = 0; ni < 2; ++ni) {
                const int row = wn * 32 + 16 * ni + a;
                bf[ni] = *reinterpret_cast<const f16x8*>(
                    &Bls[row * 128 + ((kc * 64 + g * 16) ^ ((row & 7) << 4))]);
            }
            __builtin_amdgcn_s_setprio(1);
            #pragma unroll
            for (int mi = 0; mi < 4; ++mi)
                #pragma unroll
                for (int ni = 0; ni < 2; ++ni)
                    acc[mi][ni] = __builtin_amdgcn_mfma_f32_16x16x32_f16(
                        af[mi], bf[ni], acc[mi][ni], 0, 0, 0);
            __builtin_amdgcn_s_setprio(0);
        }
        __syncthreads();
    }

    unsigned short* mydst = dst_base + (size_t)z * 4194304;

    #pragma unroll
    for (int ni = 0; ni < 2; ++ni) {
        const int n = bn + wn * 32 + 16 * ni + a;
        const float bv = bias[n];
        #pragma unroll
        for (int mi = 0; mi < 4; ++mi) {
            const int mbase = bm + wm * 64 + 16 * mi + g * 4;
            if (mode == 2) {
                const int b = mbase >> 11, s = mbase & (S_LEN - 1);
                const int h = n >> 6, d = n & (DK - 1);
                ushort4 st;
                st.x = f2h(acc[mi][ni][0] + bv);
                st.y = f2h(acc[mi][ni][1] + bv);
                st.z = f2h(acc[mi][ni][2] + bv);
                st.w = f2h(acc[mi][ni][3] + bv);
                *reinterpret_cast<ushort4*>(
                    mydst + ((size_t)((b * NHEADS + h) * DK + d)) * S_LEN + s) = st;
            } else {
                const float sc = (mode == 0) ? QSCALE : 1.0f;
                #pragma unroll
                for (int r = 0; r < 4; ++r) {
                    const int m = mbase + r;
                    const int b = m >> 11, s = m & (S_LEN - 1);
                    const int h = n >> 6, d = n & (DK - 1);
                    mydst[((size_t)((b * NHEADS + h) * S_LEN + s)) * DK + d] =
                        f2h((acc[mi][ni][r] + bv) * sc);
                }
            }
        }
    }
}

// ---------------------------------------------------------------------------
// Output GEMM (proven R15 — frozen).
// ---------------------------------------------------------------------------
__global__ __launch_bounds__(512)
void out_gemm_kernel(const unsigned short* __restrict__ Agh,
                     const unsigned short* __restrict__ Bgh,
                     const float* __restrict__ bias, float* __restrict__ out)
{
    __shared__ char Als[16384];
    __shared__ char Bls[16384];

    const char* Ag = (const char*)Agh;
    const char* Bg = (const char*)Bgh;

    const int tid = threadIdx.x;
    const int w = tid >> 6, l = tid & 63, a = l & 15, g = l >> 4;
    const int wm = w >> 2, wn = w & 3;
    const int ntile = blockIdx.y & 7;
    const int mtile = blockIdx.x + ((blockIdx.y >> 3) << 3);
    const int bm = mtile * 128, bn = ntile * 128;

    const int srow = tid >> 3;
    const int sc8 = tid & 7;

    f32x4 acc[4][2] = {};

    for (int k0b = 0; k0b < 2048; k0b += 128) {
        #pragma unroll
        for (int it = 0; it < 2; ++it) {
            const int row = it * 64 + srow;
            const int gc = (sc8 << 4) ^ ((row & 7) << 4);
            gload16(Ag + (size_t)(bm + row) * 2048 + k0b + gc,
                    &Als[(size_t)(it * 512 + tid) * 16]);
            gload16(Bg + (size_t)(bn + row) * 2048 + k0b + gc,
                    &Bls[(size_t)(it * 512 + tid) * 16]);
        }
        __syncthreads();
        #pragma unroll
        for (int kc = 0; kc < 2; ++kc) {
            f16x8 af[4], bf[2];
            #pragma unroll
            for (int mi = 0; mi < 4; ++mi) {
                const int row = wm * 64 + 16 * mi + a;
                af[mi] = *reinterpret_cast<const f16x8*>(
                    &Als[row * 128 + ((kc * 64 + g * 16) ^ ((row & 7) << 4))]);
            }
            #pragma unroll
            for (int ni = 0; ni < 2; ++ni) {
                const int row = wn * 32 + 16 * ni + a;
                bf[ni] = *reinterpret_cast<const f16x8*>(
                    &Bls[row * 128 + ((kc * 64 + g * 16) ^ ((row & 7) << 4))]);
            }
            __builtin_amdgcn_s_setprio(1);
            #pragma unroll
            for (int mi = 0; mi < 4; ++mi)
                #pragma unroll
                for (int ni = 0; ni < 2; ++ni)
                    acc[mi][ni] = __builtin_amdgcn_mfma_f32_16x16x32_f16(
                        af[mi], bf[ni], acc[mi][ni], 0, 0, 0);
            __builtin_amdgcn_s_setprio(0);
        }
        __syncthreads();
    }

    #pragma unroll
    for (int ni = 0; ni < 2; ++ni) {
        const int n = bn + wn * 32 + 16 * ni + a;
        const float bv = bias[n];
        #pragma unroll
        for (int mi = 0; mi < 4; ++mi) {
            const int mbase = bm + wm * 64 + 16 * mi + g * 4;
            #pragma unroll
            for (int r = 0; r < 4; ++r)
                out[(size_t)(mbase + r) * 1024 + n] = acc[mi][ni][r] + bv;
        }
    }
}

// ---------------------------------------------------------------------------
// MFMA flash attention v4 (exact R12/R15/R20/R22 structure — proven best).
// ---------------------------------------------------------------------------
__global__ __launch_bounds__(512, 4)
void attn_mfma_kernel(const unsigned short* __restrict__ qb,
                      const unsigned short* __restrict__ kb,
                      const unsigned short* __restrict__ vt,
                      unsigned short* __restrict__ ob)
{
    __shared__ char Kls[2][8192];
    __shared__ char Vls[2][8192];
    __shared__ unsigned short Pl[8][32][72];

    const int tid = threadIdx.x;
    const int w = tid >> 6;          // 0..7
    const int p = w >> 2;            // kv parity of this wave
    const int wsub = w & 3;
    const int l = tid & 63;
    const int a = l & 15;
    const int g = l >> 4;
    const int bh = blockIdx.y;
    const int q0 = blockIdx.x * 128 + wsub * 32;

    const unsigned short* qhead = qb + (size_t)bh * S_LEN * DK;
    const char* khead = (const char*)(kb + (size_t)bh * S_LEN * DK);
    const char* vhead = (const char*)(vt + (size_t)bh * DK * S_LEN);

    f16x8 qf[2][2];
    #pragma unroll
    for (int j = 0; j < 2; ++j)
        #pragma unroll
        for (int c = 0; c < 2; ++c)
            qf[j][c] = *reinterpret_cast<const f16x8*>(
                qhead + (size_t)(q0 + 16 * j + a) * DK + 32 * c + 8 * g);

    f16x8 onesf;
    #pragma unroll
    for (int i = 0; i < 8; ++i) onesf[i] = (_Float16)1.f;

    f32x4 oacc[4][2] = {};
    f32x4 lacc[2] = {};
    float mrun[2] = {-INFINITY, -INFINITY};

    const int srow = tid >> 3;                                  // 0..63
    const int sgc = ((tid & 7) << 4) ^ ((srow & 7) << 4);       // swizzled col

    #define STAGE1(t2)                                                          \
        do {                                                                    \
            gload16(khead + (size_t)((t2) * 64 + srow) * 128 + sgc,             \
                    &Kls[(t2) & 1][(size_t)w * 1024]);                          \
            gload16(vhead + (size_t)srow * 4096 + (size_t)(t2) * 128 + sgc,     \
                    &Vls[(t2) & 1][(size_t)w * 1024]);                          \
        } while (0)

    STAGE1(0);
    STAGE1(1);
    __syncthreads();

    for (int i = 0; i < 16; ++i) {
        f16x8 kf[2][4];
        #pragma unroll
        for (int c = 0; c < 2; ++c)
            #pragma unroll
            for (int T = 0; T < 4; ++T) {
                const int row = 16 * T + a;
                kf[c][T] = *reinterpret_cast<const f16x8*>(
                    &Kls[p][row * 128 + ((64 * c + 16 * g) ^ ((row & 7) << 4))]);
            }

        #pragma unroll
        for (int j = 0; j < 2; ++j) {
            f32x4 sacc[4] = {};
            __builtin_amdgcn_s_setprio(1);
            #pragma unroll
            for (int c = 0; c < 2; ++c)
                #pragma unroll
                for (int T = 0; T < 4; ++T)
                    sacc[T] = __builtin_amdgcn_mfma_f32_16x16x32_f16(
                        kf[c][T], qf[j][c], sacc[T], 0, 0, 0);
            __builtin_amdgcn_s_setprio(0);

            float lm = -INFINITY;
            #pragma unroll
            for (int T = 0; T < 4; ++T)
                #pragma unroll
                for (int r = 0; r < 4; ++r) lm = fmaxf(lm, sacc[T][r]);

            if (!__all(lm <= mrun[j] + 8.f)) {
                float vmax = fmaxf(lm, __shfl_xor(lm, 16));
                vmax = fmaxf(vmax, __shfl_xor(vmax, 32));
                const float mnew = fmaxf(mrun[j], vmax);
                const float corr = __builtin_amdgcn_exp2f(mrun[j] - mnew);
                #pragma unroll
                for (int t = 0; t < 4; ++t) {
                    oacc[t][j][0] *= corr; oacc[t][j][1] *= corr;
                    oacc[t][j][2] *= corr; oacc[t][j][3] *= corr;
                }
                lacc[j][0] *= corr; lacc[j][1] *= corr;
                lacc[j][2] *= corr; lacc[j][3] *= corr;
                mrun[j] = mnew;
            }

            const float mj = mrun[j];
            #pragma unroll
            for (int T = 0; T < 4; ++T) {
                float e0 = __builtin_amdgcn_exp2f(sacc[T][0] - mj);
                float e1 = __builtin_amdgcn_exp2f(sacc[T][1] - mj);
                float e2 = __builtin_amdgcn_exp2f(sacc[T][2] - mj);
                float e3 = __builtin_amdgcn_exp2f(sacc[T][3] - mj);
                unsigned* dst = reinterpret_cast<unsigned*>(
                    &Pl[w][16 * j + a][16 * T + 4 * g]);
                dst[0] = pack2(e0, e1);
                dst[1] = pack2(e2, e3);
            }
        }

        f16x8 vf[2][4];
        #pragma unroll
        for (int c = 0; c < 2; ++c)
            #pragma unroll
            for (int t = 0; t < 4; ++t) {
                const int row = 16 * t + a;
                vf[c][t] = *reinterpret_cast<const f16x8*>(
                    &Vls[p][row * 128 + ((64 * c + 16 * g) ^ ((row & 7) << 4))]);
            }

        __syncthreads();
        if (i < 15) {
            STAGE1(2 * i + 2);
            STAGE1(2 * i + 3);
        }

        #pragma unroll
        for (int c = 0; c < 2; ++c) {
            f16x8 pf[2];
            #pragma unroll
            for (int j = 0; j < 2; ++j)
                pf[j] = *reinterpret_cast<const f16x8*>(
                    &Pl[w][16 * j + a][32 * c + 8 * g]);
            __builtin_amdgcn_s_setprio(1);
            #pragma unroll
            for (int t = 0; t < 4; ++t)
                #pragma unroll
                for (int j = 0; j < 2; ++j)
                    oacc[t][j] = __builtin_amdgcn_mfma_f32_16x16x32_f16(
                        vf[c][t], pf[j], oacc[t][j], 0, 0, 0);
            #pragma unroll
            for (int j = 0; j < 2; ++j)
                lacc[j] = __builtin_amdgcn_mfma_f32_16x16x32_f16(
                    onesf, pf[j], lacc[j], 0, 0, 0);
            __builtin_amdgcn_s_setprio(0);
        }
        __syncthreads();
    }
    #undef STAGE1

    float* Ob = (float*)Pl;
    float* Ml = (float*)Kls;
    if (p == 1) {
        #pragma unroll
        for (int j = 0; j < 2; ++j) {
            if (g == 0) {
                Ml[((wsub * 2 + j) * 2 + 0) * 16 + a] = mrun[j];
                Ml[((wsub * 2 + j) * 2 + 1) * 16 + a] = lacc[j][0];
            }
            #pragma unroll
            for (int t = 0; t < 4; ++t)
                #pragma unroll
                for (int r = 0; r < 4; ++r)
                    Ob[((wsub * 2 + j) * 64 + 16 * t + 4 * g + r) * 16 + a] =
                        oacc[t][j][r];
        }
    }
    __syncthreads();
    if (p == 0) {
        const int b = bh >> 4;
        const int h = bh & (NHEADS - 1);
        #pragma unroll
        for (int j = 0; j < 2; ++j) {
            const float m1 = Ml[((wsub * 2 + j) * 2 + 0) * 16 + a];
            const float l1 = Ml[((wsub * 2 + j) * 2 + 1) * 16 + a];
            const float m0 = mrun[j];
            const float ms = fmaxf(m0, m1);
            const float c0 = __builtin_amdgcn_exp2f(m0 - ms);
            const float c1 = __builtin_amdgcn_exp2f(m1 - ms);
            const float inv = 1.f / (lacc[j][0] * c0 + l1 * c1);
            unsigned short* dst0 =
                ob + (size_t)(b * S_LEN + q0 + 16 * j + a) * DMODEL + h * DK;
            #pragma unroll
            for (int t = 0; t < 4; ++t) {
                ushort4 st;
                #pragma unroll
                for (int r = 0; r < 4; ++r) {
                    const float o1 =
                        Ob[((wsub * 2 + j) * 64 + 16 * t + 4 * g + r) * 16 + a];
                    const float val = (oacc[t][j][r] * c0 + o1 * c1) * inv;
                    ((unsigned short*)&st)[r] = f2h(val);
                }
                *reinterpret_cast<ushort4*>(dst0 + 16 * t + 4 * g) = st;
            }
        }
    }
}

// ---------------------------------------------------------------------------
extern "C" void kernel_launch(void* const* d_in, const int* in_sizes, int n_in,
                              void* d_out, int out_size, void* d_ws, size_t ws_size,
                              hipStream_t stream)
{
    const float* Q  = (const float*)d_in[0];
    const float* K  = (const float*)d_in[1];
    const float* V  = (const float*)d_in[2];
    const float* Wq = (const float*)d_in[3];
    const float* bq = (const float*)d_in[4];
    const float* Wk = (const float*)d_in[5];
    const float* bk = (const float*)d_in[6];
    const float* Wv = (const float*)d_in[7];
    const float* bv = (const float*)d_in[8];
    const float* Wo = (const float*)d_in[9];
    const float* bo = (const float*)d_in[10];
    float* out = (float*)d_out;

    // ws layout (fp16 elems): [unused 3*4M] wt[4*1M] qb[4M] kb[4M] vtb[4M] ob[4M]
    unsigned short* xh  = (unsigned short*)d_ws;
    unsigned short* wt  = xh + (size_t)3 * 4194304;
    unsigned short* qb  = wt + (size_t)4 * 1048576;
    unsigned short* kb  = qb + 4194304;
    unsigned short* vtb = kb + 4194304;
    unsigned short* obh = vtb + 4194304;

    wprep_kernel<<<dim3(16, 16, 4), 256, 0, stream>>>(Wq, Wk, Wv, Wo, wt);

    proj_gemm_kernel<<<dim3(8, 32, 3), 512, 0, stream>>>(
        Q, K, V, wt, bq, bk, bv, qb);

    attn_mfma_kernel<<<dim3(S_LEN / 128, 2 * NHEADS), 512, 0, stream>>>(qb, kb, vtb, obh);

    out_gemm_kernel<<<dim3(8, 32, 1), 512, 0, stream>>>(
        obh, wt + (size_t)3 * 1048576, bo, out);
}

// Round 25
// 119.456 us; speedup vs baseline: 1.1898x; 1.0112x over previous
//
#include <hip/hip_runtime.h>
#include <math.h>

#define S_LEN 2048
#define DMODEL 1024
#define NHEADS 16
#define DK 64

// q-projection scale: 1/sqrt(dk) * log2(e)  -> softmax works in exp2 domain
#define QSCALE 0.1803368801111244f

typedef __attribute__((ext_vector_type(8))) _Float16 f16x8;
typedef __attribute__((ext_vector_type(2))) __fp16 hf16x2;
typedef __attribute__((ext_vector_type(4))) float f32x4;

static __device__ __forceinline__ unsigned short f2h(float f) {
    _Float16 h = (_Float16)f;
    return __builtin_bit_cast(unsigned short, h);
}

static __device__ __forceinline__ unsigned pack2(float a, float b) {
    hf16x2 h = __builtin_amdgcn_cvt_pkrtz(a, b);
    return __builtin_bit_cast(unsigned, h);
}

static __device__ __forceinline__ void gload16(const void* g, void* l) {
    __builtin_amdgcn_global_load_lds(
        (const __attribute__((address_space(1))) void*)g,
        (__attribute__((address_space(3))) void*)l, 16, 0, 0);
}

// ---------------------------------------------------------------------------
// W [1024][1024] fp32 -> Wt [n][k] fp16 (transposed), LDS-tiled 64x64.
// ---------------------------------------------------------------------------
__global__ __launch_bounds__(256)
void wprep_kernel(const float* __restrict__ w0, const float* __restrict__ w1,
                  const float* __restrict__ w2, const float* __restrict__ w3,
                  unsigned short* __restrict__ wt)
{
    __shared__ float tile[64][65];
    const int z = blockIdx.z;
    const float* W = z == 0 ? w0 : (z == 1 ? w1 : (z == 2 ? w2 : w3));
    unsigned short* Wt = wt + (size_t)z * 1048576;
    const int k0 = blockIdx.x * 64, n0 = blockIdx.y * 64;
    const int t = threadIdx.x;
    #pragma unroll
    for (int i = 0; i < 4; ++i) {
        int idx = i * 256 + t;
        int r = idx >> 4, c4 = (idx & 15) * 4;
        float4 v = *reinterpret_cast<const float4*>(W + (size_t)(k0 + r) * 1024 + n0 + c4);
        tile[r][c4 + 0] = v.x; tile[r][c4 + 1] = v.y;
        tile[r][c4 + 2] = v.z; tile[r][c4 + 3] = v.w;
    }
    __syncthreads();
    #pragma unroll
    for (int i = 0; i < 4; ++i) {
        int idx = i * 256 + t;
        int nr = idx >> 4, kc4 = (idx & 15) * 4;
        ushort4 h;
        h.x = f2h(tile[kc4 + 0][nr]); h.y = f2h(tile[kc4 + 1][nr]);
        h.z = f2h(tile[kc4 + 2][nr]); h.w = f2h(tile[kc4 + 3][nr]);
        *reinterpret_cast<ushort4*>(Wt + (size_t)(n0 + nr) * 1024 + k0 + kc4) = h;
    }
}

// ---------------------------------------------------------------------------
// Fused projection GEMM (cvt in A-staging). Tile 128x128, 512 thr / 8 waves.
// XCD-aware decode (proven R15/R20/R22/R24).
// ---------------------------------------------------------------------------
__global__ __launch_bounds__(512)
void proj_gemm_kernel(const float* __restrict__ x0, const float* __restrict__ x1,
                      const float* __restrict__ x2,
                      const unsigned short* __restrict__ wt_base,
                      const float* __restrict__ b0, const float* __restrict__ b1,
                      const float* __restrict__ b2,
                      unsigned short* __restrict__ dst_base)
{
    __shared__ char Als[16384];
    __shared__ char Bls[16384];

    const int z = blockIdx.z;
    const float* Ag = z == 0 ? x0 : (z == 1 ? x1 : x2);
    const char* Bg = (const char*)(wt_base + (size_t)z * 1048576);
    const float* bias = z == 0 ? b0 : (z == 1 ? b1 : b2);
    const int mode = z;

    const int tid = threadIdx.x;
    const int w = tid >> 6, l = tid & 63, a = l & 15, g = l >> 4;
    const int wm = w >> 2, wn = w & 3;
    const int ntile = blockIdx.y & 7;
    const int mtile = blockIdx.x + ((blockIdx.y >> 3) << 3);
    const int bm = mtile * 128, bn = ntile * 128;

    const int arow = tid >> 2;
    const int ac16 = tid & 3;
    const int aswz = (arow & 7) << 4;
    const int srow = tid >> 3;
    const int sc8 = tid & 7;

    f32x4 acc[4][2] = {};

    for (int ks = 0; ks < 16; ++ks) {
        const float* ap = Ag + (size_t)(bm + arow) * 1024 + ks * 64 + 16 * ac16;
        float4 a0 = reinterpret_cast<const float4*>(ap)[0];
        float4 a1 = reinterpret_cast<const float4*>(ap)[1];
        float4 a2 = reinterpret_cast<const float4*>(ap)[2];
        float4 a3 = reinterpret_cast<const float4*>(ap)[3];

        #pragma unroll
        for (int it = 0; it < 2; ++it) {
            const int row = it * 64 + srow;
            const int gc = (sc8 << 4) ^ ((row & 7) << 4);
            gload16(Bg + (size_t)(bn + row) * 2048 + ks * 128 + gc,
                    &Bls[(size_t)(it * 512 + tid) * 16]);
        }

        uint4 w0, w1;
        w0.x = pack2(a0.x, a0.y); w0.y = pack2(a0.z, a0.w);
        w0.z = pack2(a1.x, a1.y); w0.w = pack2(a1.z, a1.w);
        w1.x = pack2(a2.x, a2.y); w1.y = pack2(a2.z, a2.w);
        w1.z = pack2(a3.x, a3.y); w1.w = pack2(a3.z, a3.w);
        const int abase = arow * 128;
        const int aoff = 32 * ac16;
        *reinterpret_cast<uint4*>(&Als[abase + (aoff ^ aswz)]) = w0;
        *reinterpret_cast<uint4*>(&Als[abase + ((aoff + 16) ^ aswz)]) = w1;

        __syncthreads();
        #pragma unroll
        for (int kc = 0; kc < 2; ++kc) {
            f16x8 af[4], bf[2];
            #pragma unroll
            for (int mi = 0; mi < 4; ++mi) {
                const int row = wm * 64 + 16 * mi + a;
                af[mi] = *reinterpret_cast<const f16x8*>(
                    &Als[row * 128 + ((kc * 64 + g * 16) ^ ((row & 7) << 4))]);
            }
            #pragma unroll
            for (int ni = 0; ni < 2; ++ni) {
                const int row = wn * 32 + 16 * ni + a;
                bf[ni] = *reinterpret_cast<const f16x8*>(
                    &Bls[row * 128 + ((kc * 64 + g * 16) ^ ((row & 7) << 4))]);
            }
            __builtin_amdgcn_s_setprio(1);
            #pragma unroll
            for (int mi = 0; mi < 4; ++mi)
                #pragma unroll
                for (int ni = 0; ni < 2; ++ni)
                    acc[mi][ni] = __builtin_amdgcn_mfma_f32_16x16x32_f16(
                        af[mi], bf[ni], acc[mi][ni], 0, 0, 0);
            __builtin_amdgcn_s_setprio(0);
        }
        __syncthreads();
    }

    unsigned short* mydst = dst_base + (size_t)z * 4194304;

    #pragma unroll
    for (int ni = 0; ni < 2; ++ni) {
        const int n = bn + wn * 32 + 16 * ni + a;
        const float bv = bias[n];
        #pragma unroll
        for (int mi = 0; mi < 4; ++mi) {
            const int mbase = bm + wm * 64 + 16 * mi + g * 4;
            if (mode == 2) {
                const int b = mbase >> 11, s = mbase & (S_LEN - 1);
                const int h = n >> 6, d = n & (DK - 1);
                ushort4 st;
                st.x = f2h(acc[mi][ni][0] + bv);
                st.y = f2h(acc[mi][ni][1] + bv);
                st.z = f2h(acc[mi][ni][2] + bv);
                st.w = f2h(acc[mi][ni][3] + bv);
                *reinterpret_cast<ushort4*>(
                    mydst + ((size_t)((b * NHEADS + h) * DK + d)) * S_LEN + s) = st;
            } else {
                const float sc = (mode == 0) ? QSCALE : 1.0f;
                #pragma unroll
                for (int r = 0; r < 4; ++r) {
                    const int m = mbase + r;
                    const int b = m >> 11, s = m & (S_LEN - 1);
                    const int h = n >> 6, d = n & (DK - 1);
                    mydst[((size_t)((b * NHEADS + h) * S_LEN + s)) * DK + d] =
                        f2h((acc[mi][ni][r] + bv) * sc);
                }
            }
        }
    }
}

// ---------------------------------------------------------------------------
// Output GEMM (proven R15 — frozen).
// ---------------------------------------------------------------------------
__global__ __launch_bounds__(512)
void out_gemm_kernel(const unsigned short* __restrict__ Agh,
                     const unsigned short* __restrict__ Bgh,
                     const float* __restrict__ bias, float* __restrict__ out)
{
    __shared__ char Als[16384];
    __shared__ char Bls[16384];

    const char* Ag = (const char*)Agh;
    const char* Bg = (const char*)Bgh;

    const int tid = threadIdx.x;
    const int w = tid >> 6, l = tid & 63, a = l & 15, g = l >> 4;
    const int wm = w >> 2, wn = w & 3;
    const int ntile = blockIdx.y & 7;
    const int mtile = blockIdx.x + ((blockIdx.y >> 3) << 3);
    const int bm = mtile * 128, bn = ntile * 128;

    const int srow = tid >> 3;
    const int sc8 = tid & 7;

    f32x4 acc[4][2] = {};

    for (int k0b = 0; k0b < 2048; k0b += 128) {
        #pragma unroll
        for (int it = 0; it < 2; ++it) {
            const int row = it * 64 + srow;
            const int gc = (sc8 << 4) ^ ((row & 7) << 4);
            gload16(Ag + (size_t)(bm + row) * 2048 + k0b + gc,
                    &Als[(size_t)(it * 512 + tid) * 16]);
            gload16(Bg + (size_t)(bn + row) * 2048 + k0b + gc,
                    &Bls[(size_t)(it * 512 + tid) * 16]);
        }
        __syncthreads();
        #pragma unroll
        for (int kc = 0; kc < 2; ++kc) {
            f16x8 af[4], bf[2];
            #pragma unroll
            for (int mi = 0; mi < 4; ++mi) {
                const int row = wm * 64 + 16 * mi + a;
                af[mi] = *reinterpret_cast<const f16x8*>(
                    &Als[row * 128 + ((kc * 64 + g * 16) ^ ((row & 7) << 4))]);
            }
            #pragma unroll
            for (int ni = 0; ni < 2; ++ni) {
                const int row = wn * 32 + 16 * ni + a;
                bf[ni] = *reinterpret_cast<const f16x8*>(
                    &Bls[row * 128 + ((kc * 64 + g * 16) ^ ((row & 7) << 4))]);
            }
            __builtin_amdgcn_s_setprio(1);
            #pragma unroll
            for (int mi = 0; mi < 4; ++mi)
                #pragma unroll
                for (int ni = 0; ni < 2; ++ni)
                    acc[mi][ni] = __builtin_amdgcn_mfma_f32_16x16x32_f16(
                        af[mi], bf[ni], acc[mi][ni], 0, 0, 0);
            __builtin_amdgcn_s_setprio(0);
        }
        __syncthreads();
    }

    #pragma unroll
    for (int ni = 0; ni < 2; ++ni) {
        const int n = bn + wn * 32 + 16 * ni + a;
        const float bv = bias[n];
        #pragma unroll
        for (int mi = 0; mi < 4; ++mi) {
            const int mbase = bm + wm * 64 + 16 * mi + g * 4;
            #pragma unroll
            for (int r = 0; r < 4; ++r)
                out[(size_t)(mbase + r) * 1024 + n] = acc[mi][ni][r] + bv;
        }
    }
}

// ---------------------------------------------------------------------------
// MFMA flash attention v4 + T1 grid swizzle: grid is (head=32, qtile=16) so
// dispatch id mod 8 = head mod 8 — all 16 q-tile blocks of a head land on
// the SAME XCD and share its K/V panel (512 KB) from that XCD's L2 instead
// of refetching it on up to 8 XCDs. Kernel body otherwise identical to the
// proven R12/R15/R20/R22 structure.
// ---------------------------------------------------------------------------
__global__ __launch_bounds__(512, 4)
void attn_mfma_kernel(const unsigned short* __restrict__ qb,
                      const unsigned short* __restrict__ kb,
                      const unsigned short* __restrict__ vt,
                      unsigned short* __restrict__ ob)
{
    __shared__ char Kls[2][8192];
    __shared__ char Vls[2][8192];
    __shared__ unsigned short Pl[8][32][72];

    const int tid = threadIdx.x;
    const int w = tid >> 6;          // 0..7
    const int p = w >> 2;            // kv parity of this wave
    const int wsub = w & 3;
    const int l = tid & 63;
    const int a = l & 15;
    const int g = l >> 4;
    const int bh = blockIdx.x;                       // T1: head on fast axis
    const int q0 = blockIdx.y * 128 + wsub * 32;     //     q-tile on slow axis

    const unsigned short* qhead = qb + (size_t)bh * S_LEN * DK;
    const char* khead = (const char*)(kb + (size_t)bh * S_LEN * DK);
    const char* vhead = (const char*)(vt + (size_t)bh * DK * S_LEN);

    f16x8 qf[2][2];
    #pragma unroll
    for (int j = 0; j < 2; ++j)
        #pragma unroll
        for (int c = 0; c < 2; ++c)
            qf[j][c] = *reinterpret_cast<const f16x8*>(
                qhead + (size_t)(q0 + 16 * j + a) * DK + 32 * c + 8 * g);

    f16x8 onesf;
    #pragma unroll
    for (int i = 0; i < 8; ++i) onesf[i] = (_Float16)1.f;

    f32x4 oacc[4][2] = {};
    f32x4 lacc[2] = {};
    float mrun[2] = {-INFINITY, -INFINITY};

    const int srow = tid >> 3;                                  // 0..63
    const int sgc = ((tid & 7) << 4) ^ ((srow & 7) << 4);       // swizzled col

    #define STAGE1(t2)                                                          \
        do {                                                                    \
            gload16(khead + (size_t)((t2) * 64 + srow) * 128 + sgc,             \
                    &Kls[(t2) & 1][(size_t)w * 1024]);                          \
            gload16(vhead + (size_t)srow * 4096 + (size_t)(t2) * 128 + sgc,     \
                    &Vls[(t2) & 1][(size_t)w * 1024]);                          \
        } while (0)

    STAGE1(0);
    STAGE1(1);
    __syncthreads();

    for (int i = 0; i < 16; ++i) {
        f16x8 kf[2][4];
        #pragma unroll
        for (int c = 0; c < 2; ++c)
            #pragma unroll
            for (int T = 0; T < 4; ++T) {
                const int row = 16 * T + a;
                kf[c][T] = *reinterpret_cast<const f16x8*>(
                    &Kls[p][row * 128 + ((64 * c + 16 * g) ^ ((row & 7) << 4))]);
            }

        #pragma unroll
        for (int j = 0; j < 2; ++j) {
            f32x4 sacc[4] = {};
            __builtin_amdgcn_s_setprio(1);
            #pragma unroll
            for (int c = 0; c < 2; ++c)
                #pragma unroll
                for (int T = 0; T < 4; ++T)
                    sacc[T] = __builtin_amdgcn_mfma_f32_16x16x32_f16(
                        kf[c][T], qf[j][c], sacc[T], 0, 0, 0);
            __builtin_amdgcn_s_setprio(0);

            float lm = -INFINITY;
            #pragma unroll
            for (int T = 0; T < 4; ++T)
                #pragma unroll
                for (int r = 0; r < 4; ++r) lm = fmaxf(lm, sacc[T][r]);

            if (!__all(lm <= mrun[j] + 8.f)) {
                float vmax = fmaxf(lm, __shfl_xor(lm, 16));
                vmax = fmaxf(vmax, __shfl_xor(vmax, 32));
                const float mnew = fmaxf(mrun[j], vmax);
                const float corr = __builtin_amdgcn_exp2f(mrun[j] - mnew);
                #pragma unroll
                for (int t = 0; t < 4; ++t) {
                    oacc[t][j][0] *= corr; oacc[t][j][1] *= corr;
                    oacc[t][j][2] *= corr; oacc[t][j][3] *= corr;
                }
                lacc[j][0] *= corr; lacc[j][1] *= corr;
                lacc[j][2] *= corr; lacc[j][3] *= corr;
                mrun[j] = mnew;
            }

            const float mj = mrun[j];
            #pragma unroll
            for (int T = 0; T < 4; ++T) {
                float e0 = __builtin_amdgcn_exp2f(sacc[T][0] - mj);
                float e1 = __builtin_amdgcn_exp2f(sacc[T][1] - mj);
                float e2 = __builtin_amdgcn_exp2f(sacc[T][2] - mj);
                float e3 = __builtin_amdgcn_exp2f(sacc[T][3] - mj);
                unsigned* dst = reinterpret_cast<unsigned*>(
                    &Pl[w][16 * j + a][16 * T + 4 * g]);
                dst[0] = pack2(e0, e1);
                dst[1] = pack2(e2, e3);
            }
        }

        f16x8 vf[2][4];
        #pragma unroll
        for (int c = 0; c < 2; ++c)
            #pragma unroll
            for (int t = 0; t < 4; ++t) {
                const int row = 16 * t + a;
                vf[c][t] = *reinterpret_cast<const f16x8*>(
                    &Vls[p][row * 128 + ((64 * c + 16 * g) ^ ((row & 7) << 4))]);
            }

        __syncthreads();
        if (i < 15) {
            STAGE1(2 * i + 2);
            STAGE1(2 * i + 3);
        }

        #pragma unroll
        for (int c = 0; c < 2; ++c) {
            f16x8 pf[2];
            #pragma unroll
            for (int j = 0; j < 2; ++j)
                pf[j] = *reinterpret_cast<const f16x8*>(
                    &Pl[w][16 * j + a][32 * c + 8 * g]);
            __builtin_amdgcn_s_setprio(1);
            #pragma unroll
            for (int t = 0; t < 4; ++t)
                #pragma unroll
                for (int j = 0; j < 2; ++j)
                    oacc[t][j] = __builtin_amdgcn_mfma_f32_16x16x32_f16(
                        vf[c][t], pf[j], oacc[t][j], 0, 0, 0);
            #pragma unroll
            for (int j = 0; j < 2; ++j)
                lacc[j] = __builtin_amdgcn_mfma_f32_16x16x32_f16(
                    onesf, pf[j], lacc[j], 0, 0, 0);
            __builtin_amdgcn_s_setprio(0);
        }
        __syncthreads();
    }
    #undef STAGE1

    float* Ob = (float*)Pl;
    float* Ml = (float*)Kls;
    if (p == 1) {
        #pragma unroll
        for (int j = 0; j < 2; ++j) {
            if (g == 0) {
                Ml[((wsub * 2 + j) * 2 + 0) * 16 + a] = mrun[j];
                Ml[((wsub * 2 + j) * 2 + 1) * 16 + a] = lacc[j][0];
            }
            #pragma unroll
            for (int t = 0; t < 4; ++t)
                #pragma unroll
                for (int r = 0; r < 4; ++r)
                    Ob[((wsub * 2 + j) * 64 + 16 * t + 4 * g + r) * 16 + a] =
                        oacc[t][j][r];
        }
    }
    __syncthreads();
    if (p == 0) {
        const int b = bh >> 4;
        const int h = bh & (NHEADS - 1);
        #pragma unroll
        for (int j = 0; j < 2; ++j) {
            const float m1 = Ml[((wsub * 2 + j) * 2 + 0) * 16 + a];
            const float l1 = Ml[((wsub * 2 + j) * 2 + 1) * 16 + a];
            const float m0 = mrun[j];
            const float ms = fmaxf(m0, m1);
            const float c0 = __builtin_amdgcn_exp2f(m0 - ms);
            const float c1 = __builtin_amdgcn_exp2f(m1 - ms);
            const float inv = 1.f / (lacc[j][0] * c0 + l1 * c1);
            unsigned short* dst0 =
                ob + (size_t)(b * S_LEN + q0 + 16 * j + a) * DMODEL + h * DK;
            #pragma unroll
            for (int t = 0; t < 4; ++t) {
                ushort4 st;
                #pragma unroll
                for (int r = 0; r < 4; ++r) {
                    const float o1 =
                        Ob[((wsub * 2 + j) * 64 + 16 * t + 4 * g + r) * 16 + a];
                    const float val = (oacc[t][j][r] * c0 + o1 * c1) * inv;
                    ((unsigned short*)&st)[r] = f2h(val);
                }
                *reinterpret_cast<ushort4*>(dst0 + 16 * t + 4 * g) = st;
            }
        }
    }
}

// ---------------------------------------------------------------------------
extern "C" void kernel_launch(void* const* d_in, const int* in_sizes, int n_in,
                              void* d_out, int out_size, void* d_ws, size_t ws_size,
                              hipStream_t stream)
{
    const float* Q  = (const float*)d_in[0];
    const float* K  = (const float*)d_in[1];
    const float* V  = (const float*)d_in[2];
    const float* Wq = (const float*)d_in[3];
    const float* bq = (const float*)d_in[4];
    const float* Wk = (const float*)d_in[5];
    const float* bk = (const float*)d_in[6];
    const float* Wv = (const float*)d_in[7];
    const float* bv = (const float*)d_in[8];
    const float* Wo = (const float*)d_in[9];
    const float* bo = (const float*)d_in[10];
    float* out = (float*)d_out;

    // ws layout (fp16 elems): [unused 3*4M] wt[4*1M] qb[4M] kb[4M] vtb[4M] ob[4M]
    unsigned short* xh  = (unsigned short*)d_ws;
    unsigned short* wt  = xh + (size_t)3 * 4194304;
    unsigned short* qb  = wt + (size_t)4 * 1048576;
    unsigned short* kb  = qb + 4194304;
    unsigned short* vtb = kb + 4194304;
    unsigned short* obh = vtb + 4194304;

    wprep_kernel<<<dim3(16, 16, 4), 256, 0, stream>>>(Wq, Wk, Wv, Wo, wt);

    proj_gemm_kernel<<<dim3(8, 32, 3), 512, 0, stream>>>(
        Q, K, V, wt, bq, bk, bv, qb);

    // T1: grid (head, qtile) so each head's 16 blocks share one XCD's L2
    attn_mfma_kernel<<<dim3(2 * NHEADS, S_LEN / 128), 512, 0, stream>>>(qb, kb, vtb, obh);

    out_gemm_kernel<<<dim3(8, 32, 1), 512, 0, stream>>>(
        obh, wt + (size_t)3 * 1048576, bo, out);
}